// Round 9
// baseline (157.359 us; speedup 1.0000x reference)
//
#include <hip/hip_runtime.h>
#include <stdint.h>

// ENAS LSTM controller. R20: sampling folded into the exchange window.
//  - R19 post-mortem: fused nonlin kept (R18 had it at 85-86us warm; R19's
//    99us rocprof run was environmental — hbm_gbps uniformly -15% at equal
//    traffic, acquire 54s). Official bench best: 146.8us.
//  - R20 change: wg0's resolve (logits -> selection -> idx publish) ran
//    SERIALLY after each mode-0 cell's closing barrier — on the chain's
//    pacing wg (wg0 also gathers y, so every h-exchange syncs to it).
//    Now waves 4-7 of wg0 sample INSIDE the mode-0 cell's exchange phase:
//    after writing w2hS from the y-gather (waves 0-3 still h-polling),
//    LDS-atomic mini-sync (monotonic counters; s_barrier would deadlock
//    vs polling waves), logits (wave u does wv=u,u+4 — per-wv FP sequence
//    identical to R16), sync2, wave 4 runs the R10 selection verbatim
//    (lane=tid-256) and publishes the idx word BEFORE the closing barrier.
//    wg0 then reads selL directly (no resolve); peers unchanged (dotHH
//    overlapped with idx poll). lpAcc/entAcc move to tid==256, which owns
//    the final output block.
//  - Idx publish ~1us earlier x10 sampled cells, all off the pacing path.
//  - Falsified-levers ledger: XCD-L2 transport (R14), decentralized
//    sampling (R12/R13/R17), gather batching beyond R16 (R15/R16),
//    peer-side compute compression (R18). The 15-RT exchange chain is
//    structural; this targets the last serialized work on it.
//  - ws layout = R16 (221,504 <= proven 221,696); R8 fallback kept.

#define NBLK  6
#define PWG   8
#define THR   512
#define TINYF 1.17549435e-38f
#define HTAGB 0xC3B00000u
#define YTAGB 0xE1700000u
#define ITAGB 0xA5D00000u
#define DONE_MAGIC 0x444f4e45

typedef unsigned long long u64;
struct U2 { uint32_t x, y; };

// ---- ws layout (bytes) ----
#define W_DONE 0u        // int[8]                (32)
#define W_PART 32u       // float[12]             (48)
#define W_IDX  80u       // u32[6][10] = 240
#define W_HX   320u      // u64[2][6][256] = 24576
#define W_YMB  24896u    // u64[2][6][8][256] = 196608 (64B-aligned)
#define W_NEED 221504u

// ---- fallback (R8/R10 small) ws layout ----
#define S_READY 0u
#define S_DONE  192u
#define S_PART  224u
#define S_HP    320u
#define S_ACC   24896u
#define FXS     67108864.0f
#define READY_MAGIC 0x52454459

// Threefry-2x32, 20 rounds (Random123 / JAX). Key (k0,k1), counter (c0,c1).
__device__ __forceinline__ U2 tf2x32(uint32_t k0, uint32_t k1,
                                     uint32_t c0, uint32_t c1) {
  uint32_t ks2 = k0 ^ k1 ^ 0x1BD11BDAu;
  uint32_t x0 = c0 + k0, x1 = c1 + k1;
#define TFR(r) { x0 += x1; x1 = (x1 << (r)) | (x1 >> (32 - (r))); x1 ^= x0; }
  TFR(13) TFR(15) TFR(26) TFR(6)   x0 += k1;  x1 += ks2 + 1u;
  TFR(17) TFR(29) TFR(16) TFR(24)  x0 += ks2; x1 += k0 + 2u;
  TFR(13) TFR(15) TFR(26) TFR(6)   x0 += k0;  x1 += k1 + 3u;
  TFR(17) TFR(29) TFR(16) TFR(24)  x0 += k1;  x1 += ks2 + 4u;
  TFR(13) TFR(15) TFR(26) TFR(6)   x0 += ks2; x1 += k0 + 5u;
#undef TFR
  U2 r; r.x = x0; r.y = x1; return r;
}

__device__ __forceinline__ float sigf(float x) {
  return 1.0f / (1.0f + expf(-x));
}
// relaxed agent-scope (LLC-resolved) accessors -- the only sync primitives.
__device__ __forceinline__ void istore(int* p, int v) {
  __hip_atomic_store(p, v, __ATOMIC_RELAXED, __HIP_MEMORY_SCOPE_AGENT);
}
__device__ __forceinline__ int iload(const int* p) {
  return __hip_atomic_load(p, __ATOMIC_RELAXED, __HIP_MEMORY_SCOPE_AGENT);
}
__device__ __forceinline__ void hstore(u64* p, u64 v) {
  __hip_atomic_store(p, v, __ATOMIC_RELAXED, __HIP_MEMORY_SCOPE_AGENT);
}
__device__ __forceinline__ u64 hload(const u64* p) {
  return __hip_atomic_load(p, __ATOMIC_RELAXED, __HIP_MEMORY_SCOPE_AGENT);
}
__device__ __forceinline__ void fstore(float* p, float v) {
  __hip_atomic_store(p, v, __ATOMIC_RELAXED, __HIP_MEMORY_SCOPE_AGENT);
}
__device__ __forceinline__ float fload(const float* p) {
  return __hip_atomic_load(p, __ATOMIC_RELAXED, __HIP_MEMORY_SCOPE_AGENT);
}
__device__ __forceinline__ u64 pollw(const u64* p, uint32_t want) {
  u64 v;
  for (;;) {
    v = hload(p);
    if ((uint32_t)(v >> 32) == want) return v;
    __builtin_amdgcn_s_sleep(1);
  }
}

// =================== R20 kernel ============================================
__global__ __launch_bounds__(THR, 2) void ctrl_v20(
    const float* __restrict__ enc_w,
    const float* __restrict__ wih,
    const float* __restrict__ whh,
    const float* __restrict__ b_ih,
    const float* __restrict__ b_hh,
    const float* __restrict__ w1,
    const float* __restrict__ w2,
    const float* __restrict__ vvec,
    unsigned char* __restrict__ ws,
    float* __restrict__ out) {

  const int b = blockIdx.x & 7;      // XCD swizzle: chain b -> XCD b (if RR)
  const int p = blockIdx.x >> 3;
  if (b >= NBLK) return;
  const int tid = threadIdx.x;

  int*   done = (int*)(ws + W_DONE);
  float* part = (float*)(ws + W_PART);
  int*   idxw = (int*)(ws + W_IDX);   // u32 self-validating idx words
  u64*   hx   = (u64*)(ws + W_HX);    // [2][6][256] tagged h words
  u64*   ymb  = (u64*)(ws + W_YMB);   // [2][6][8][256] tagged y words

  // gate GEMV: 128 local rows x 4 k-slices of 64; s wave-uniform -> all LDS
  // x-vector reads are broadcasts (0 bank conflicts, proven R11/R16).
  const int rl = tid & 127, s = tid >> 7;
  const int grow = (rl >> 5) * 256 + p * 32 + (rl & 31);
  const int k0 = s * 64;
  // y-partial: element rr, col half ks (cols p*32 + ks*16 + j)
  const int rr = tid & 255, ks = tid >> 8;
  const int cb = p * 32 + ks * 16;

  __shared__ __align__(16) float gateL[THR];
  __shared__ __align__(16) float hL[256], encL[256], vL[256];
  __shared__ __align__(16) float anchL[4][256];
  __shared__ __align__(16) float w2hS[256], aw1S[6][256];
  __shared__ float biasS[128], h2S[32];
  __shared__ float logitL[8];
  __shared__ int   selL;
  __shared__ int   upC1, upC2;       // monotonic upper-wave sync counters

  if (tid < 256) { encL[tid] = enc_w[tid]; vL[tid] = vvec[tid]; }
  if (tid < 128) {
    int r = (tid >> 5) * 256 + p * 32 + (tid & 31);
    biasS[tid] = b_ih[r] + b_hh[r];
  }
  if (tid == 0) { upC1 = 0; upC2 = 0; }

  // weights: unified VGPR/AGPR file keeps these resident (R11-proven)
  float4 wihr[16], whhr[16];
  #pragma unroll
  for (int c = 0; c < 16; ++c) {
    wihr[c] = *(const float4*)(wih + grow * 256 + k0 + c * 4);
    whhr[c] = *(const float4*)(whh + grow * 256 + k0 + c * 4);
  }
  float w1c[16], w2c[16];
  #pragma unroll
  for (int j = 0; j < 16; ++j) {
    w1c[j] = w1[rr * 256 + cb + j];
    w2c[j] = w2[rr * 256 + cb + j];
  }
  __syncthreads();

  auto dotIH = [&](const float* x) {
    float a = 0.0f;
    #pragma unroll
    for (int c = 0; c < 16; ++c) {
      float4 xv = *(const float4*)(x + k0 + c * 4);
      float4 w = wihr[c];
      a += w.x * xv.x + w.y * xv.y + w.z * xv.z + w.w * xv.w;
    }
    return a;
  };
  auto dotHH = [&]() {
    float a = 0.0f;
    #pragma unroll
    for (int c = 0; c < 16; ++c) {
      float4 xv = *(const float4*)(hL + k0 + c * 4);
      float4 w = whhr[c];
      a += w.x * xv.x + w.y * xv.y + w.z * xv.z + w.w * xv.w;
    }
    return a;
  };

  const float encih = dotIH(encL);   // wih @ enc, reused by all enc cells

  float cv = 0.0f;                            // c for element p*32+tid (tid<32)
  U2 bk = tf2x32(0u, 42u, 0u, (uint32_t)b);   // fold_in(key(42), b)
  int k = 1, step = 0;
  int upT1 = 0, upT2 = 0;                     // per-thread sync targets (wg0)
  float lpAcc = 0.0f, entAcc = 0.0f;          // live in tid==256 of wg0

  // One cell + exchange. mode 0: y = w2@h -> w2hS (wg0); mode 1: y = w1@h
  // -> aw1S[aid] (wg0) + anchor h -> anchL[cid] (all); mode 2: last cell.
  // sampL>0 (mode-0 only): wg0's waves 4-7 sample INSIDE the exchange and
  // publish the idx word before the closing barrier.
  auto cell = [&](float gacc, int mode, int aid, int cid, int sampL) {
    gateL[tid] = gacc;                       // tid = s*128 + rl
    __syncthreads();
    if (tid < 32) {                          // fused reduce+nonlin (R18/R19)
      float rs[4];
      #pragma unroll
      for (int g = 0; g < 4; ++g) {
        float ssum = 0.0f;
        #pragma unroll
        for (int j = 0; j < 4; ++j) ssum += gateL[j * 128 + g * 32 + tid];
        rs[g] = ssum + biasS[g * 32 + tid];
      }
      float gi = rs[0], gf = rs[1], gg2 = rs[2], go = rs[3];
      float c2 = sigf(gf) * cv + sigf(gi) * tanhf(gg2);
      float h2 = sigf(go) * tanhf(c2);
      cv = c2;
      h2S[tid] = h2;
      if (mode == 2) {
        if (b == NBLK - 1) { out[62 + p * 32 + tid] = cv; out[318 + p * 32 + tid] = h2; }
      } else {                               // publish own h ASAP (tagged)
        hstore(&hx[(k & 1) * 1536 + b * 256 + p * 32 + tid],
               ((u64)(HTAGB | (uint32_t)k) << 32) | (u64)__float_as_uint(h2));
      }
    }
    __syncthreads();                         // h2S visible; gateL reusable
    if (mode == 2) return;

    {                                        // own y partial (16 cols each)
      const float* wc = (mode == 1) ? w1c : w2c;
      float yp = 0.0f;
      #pragma unroll
      for (int j = 0; j < 16; ++j) yp += wc[j] * h2S[ks * 16 + j];
      gateL[tid] = yp;                       // layout ks*256 + rr
    }
    __syncthreads();

    const uint32_t wantY = YTAGB | (uint32_t)k;
    const uint32_t wantH = HTAGB | (uint32_t)k;
    u64* ybase = ymb + (size_t)(k & 1) * 12288 + (size_t)b * 2048; // [8][256]
    if (tid < 256) {
      // publish self-validating y word: (tag|f32), value = A+B bits == R16.
      float yp2 = gateL[tid] + gateL[256 + tid];
      hstore(ybase + (size_t)p * 256 + tid,
             ((u64)wantY << 32) | (u64)__float_as_uint(yp2));
      // then poll full h (each lane stops once its word is valid)
      u64 v = pollw(&hx[(k & 1) * 1536 + b * 256 + tid], wantH);
      float hv = __uint_as_float((uint32_t)v);
      hL[tid] = hv;
      if (mode == 1 && cid >= 0) anchL[cid][tid] = hv;
    } else if (p == 0) {
      // wg0 waves 4-7: gather the 8 y partials for element e concurrently
      // with the h-poll (one batched RT), then — if sampling — run the
      // logits + selection here, overlapped with waves 0-3's h-poll.
      const int e = tid - 256;
      const u64* bp = ybase + e;
      u64 w[8];
      for (;;) {
        #pragma unroll
        for (int q = 0; q < 8; ++q) w[q] = hload(bp + q * 256);
        uint32_t bad = 0u;
        #pragma unroll
        for (int q = 0; q < 8; ++q) bad |= ((uint32_t)(w[q] >> 32) ^ wantY);
        if (bad == 0u) break;
        __builtin_amdgcn_s_sleep(1);
      }
      float y = 0.0f;
      #pragma unroll
      for (int q = 0; q < 8; ++q) y += __uint_as_float((uint32_t)w[q]);
      if (mode == 1) aw1S[aid][e] = y; else w2hS[e] = y;

      if (sampL > 0) {
        // sync1: all 4 upper waves' w2hS writes visible (LDS is un-cached;
        // per-wave DS ordering + explicit lgkmcnt drain before the atomic).
        asm volatile("s_waitcnt lgkmcnt(0)" ::: "memory");
        if ((tid & 63) == 0)
          __hip_atomic_fetch_add(&upC1, 1, __ATOMIC_RELEASE,
                                 __HIP_MEMORY_SCOPE_WORKGROUP);
        upT1 += 4;
        while (__hip_atomic_load(&upC1, __ATOMIC_ACQUIRE,
                                 __HIP_MEMORY_SCOPE_WORKGROUP) < upT1) {}
        const int uw = e >> 6, lane = tid & 63;
        for (int wv = uw; wv < sampL; wv += 4) {   // per-wv math == R16
          float a = 0.0f;
          #pragma unroll
          for (int j = 0; j < 4; ++j) {            // stride-64: conflict-free
            int kk = j * 64 + lane;
            a += tanhf(aw1S[wv][kk] + w2hS[kk]) * vL[kk];
          }
          a += __shfl_down(a, 32);
          a += __shfl_down(a, 16);
          a += __shfl_down(a, 8);
          a += __shfl_down(a, 4);
          a += __shfl_down(a, 2);
          a += __shfl_down(a, 1);
          if (lane == 0) logitL[wv] = a;
        }
        // sync2: logitL complete across upper waves.
        asm volatile("s_waitcnt lgkmcnt(0)" ::: "memory");
        if ((tid & 63) == 0)
          __hip_atomic_fetch_add(&upC2, 1, __ATOMIC_RELEASE,
                                 __HIP_MEMORY_SCOPE_WORKGROUP);
        upT2 += 4;
        while (__hip_atomic_load(&upC2, __ATOMIC_ACQUIRE,
                                 __HIP_MEMORY_SCOPE_WORKGROUP) < upT2) {}
        if (uw == 0) {                       // wave 4: selection (R10 math)
          float lg = 0.0f, sgum = -1e30f;
          if (lane < sampL) {
            lg = 1.1f * tanhf(logitL[lane] * 0.2f);
            U2 sk = tf2x32(bk.x, bk.y, 0u, (uint32_t)step);
            U2 r2 = tf2x32(sk.x, sk.y, 0u, (uint32_t)lane);
            uint32_t bits = r2.x ^ r2.y;
            float u = __uint_as_float((bits >> 9) | 0x3f800000u) - 1.0f;
            u = fmaxf(TINYF, u + TINYF);     // jax uniform(tiny, 1)
            sgum = lg - logf(-logf(u));
          }
          int bi = 0;
          float best = __shfl(sgum, 0, 64);
          for (int j = 1; j < sampL; ++j) {
            float sj = __shfl(sgum, j, 64);
            if (sj > best) { best = sj; bi = j; }  // first-max = jnp.argmax
          }
          float mx = __shfl(lg, 0, 64);
          for (int j = 1; j < sampL; ++j) mx = fmaxf(mx, __shfl(lg, j, 64));
          float se = 0.0f;
          for (int j = 0; j < sampL; ++j) se += expf(__shfl(lg, j, 64) - mx);
          float lse = logf(se);
          float lgbi = __shfl(lg, bi, 64);
          float es = 0.0f;
          for (int j = 0; j < sampL; ++j) {
            float l = __shfl(lg, j, 64) - mx - lse;
            es += l * expf(l);
          }
          if (lane == 0) {                   // tid == 256
            lpAcc += -(lgbi - mx - lse);
            entAcc += -es;
            selL = bi;
            out[b * 10 + step] = (float)bi;
            istore(&idxw[b * 10 + step],
                   (int)(ITAGB | ((uint32_t)step << 4) | (uint32_t)bi));
          }
        }
      }
    }
    __syncthreads();
    if (sampL > 0 && p == 0) ++step;         // wg0 consumed one sample slot
    ++k;
  };

  // peers: poll the self-validating idx word (published early by wg0).
  auto resolve = [&](int L) -> int {
    (void)L;
    if (tid == 0) {
      const uint32_t want = ITAGB | ((uint32_t)step << 4);
      for (;;) {
        uint32_t v = (uint32_t)iload(&idxw[b * 10 + step]);
        if ((v & 0xFFFFFFF0u) == want) { selL = (int)(v & 15u); break; }
        __builtin_amdgcn_s_sleep(1);
      }
    }
    __syncthreads();
    step++;
    return selL;
  };

  // ---- chain ----
  cell(encih, 1, 0, -1, 0);          // zero-state cell; wg0 gets aw1[0]
  if (p == 0) {
    if (tid < 256) aw1S[1][tid] = aw1S[0][tid];
    __syncthreads();
  }

  for (int L = 2; L <= 6; ++L) {
    { float hh = dotHH(); cell(encih + hh, 0, 0, -1, L); }       // cellA+s1
    {
      int s1; float hh;
      if (p == 0) { s1 = selL; hh = dotHH(); }                   // sampled in cellA
      else        { hh = dotHH(); s1 = resolve(L); }             // overlap wait
      float a = (s1 >= 2) ? dotIH(&anchL[s1 - 2][0]) : 0.0f;
      cell(a + hh, 0, 0, -1, L);                                 // cellB+s2
    }
    {
      int s2; float hh;
      if (p == 0) { s2 = selL; hh = dotHH(); }
      else        { hh = dotHH(); s2 = resolve(L); }
      float a = (s2 >= 2) ? dotIH(&anchL[s2 - 2][0]) : 0.0f;
      if (L < 6) cell(a + hh, 1, L, L - 2, 0);                   // cellC anchor
      else       cell(a + hh, 2, 0, -1, 0);                      // last cell
    }
  }

  if (p == 0 && tid == 256) {        // accumulators live in tid==256 now
    fstore(&part[2 * b], lpAcc);
    fstore(&part[2 * b + 1], entAcc);
    __builtin_amdgcn_s_waitcnt(0);
    istore(&done[b], DONE_MAGIC);
    if (b == NBLK - 1) {
      float lp = 0.0f, en = 0.0f;
      for (int j = 0; j < NBLK; ++j) {
        while (iload(&done[j]) != DONE_MAGIC) __builtin_amdgcn_s_sleep(1);
        lp += fload(&part[2 * j]);
        en += fload(&part[2 * j + 1]);
      }
      out[60] = lp;
      out[61] = en;
    }
  }
}

// =================== fallback (proven R8-style; small ws) ==================
__global__ __launch_bounds__(1024) void ctrl_small(
    const float* __restrict__ enc_w,
    const float* __restrict__ wih,
    const float* __restrict__ whh,
    const float* __restrict__ b_ih,
    const float* __restrict__ b_hh,
    const float* __restrict__ w1,
    const float* __restrict__ w2,
    const float* __restrict__ vvec,
    unsigned char* __restrict__ ws,
    float* __restrict__ out) {

  const int b = blockIdx.x & 7;
  const int p = blockIdx.x >> 3;
  if (b >= NBLK) return;
  const int tid = threadIdx.x;

  int*   ready = (int*)(ws + S_READY);
  int*   done  = (int*)(ws + S_DONE);
  float* part  = (float*)(ws + S_PART);
  u64*   hp    = (u64*)(ws + S_HP);
  int*   acc   = (int*)(ws + S_ACC);

  const int rl = tid >> 3, s = tid & 7;
  const int g = rl >> 5, el = rl & 31;
  const int row = g * 256 + p * 32 + el;
  const int k0 = s * 32;
  const int rr = tid & 255, ks = tid >> 8;

  __shared__ __align__(16) float hL[256], encL[256], vL[256];
  __shared__ __align__(16) float anchL[4][256];
  __shared__ __align__(16) float partL[1024];
  __shared__ __align__(16) float w2hS[256], aw1S[6][256];
  __shared__ float rowSumL[128], biasS[128], h2S[32];
  __shared__ float logitL[8];
  __shared__ int   selL;

  if (tid < 256) { encL[tid] = enc_w[tid]; vL[tid] = vvec[tid]; }
  if (tid < 128) {
    int gg = tid >> 5, ee = tid & 31, r = gg * 256 + p * 32 + ee;
    biasS[tid] = b_ih[r] + b_hh[r];
  }

  float4 wihr[8], whhr[8];
  #pragma unroll
  for (int c = 0; c < 8; ++c) {
    int cc = (c + s) & 7;
    wihr[c] = *(const float4*)(wih + row * 256 + k0 + cc * 4);
    whhr[c] = *(const float4*)(whh + row * 256 + k0 + cc * 4);
  }
  float w1c[8], w2c[8];
  #pragma unroll
  for (int j = 0; j < 8; ++j) {
    w1c[j] = w1[rr * 256 + p * 32 + ks * 8 + j];
    w2c[j] = w2[rr * 256 + p * 32 + ks * 8 + j];
  }

  if (tid < 32) istore(&acc[1 * (NBLK * 256) + b * 256 + p * 32 + tid], 0);
  __syncthreads();
  if (tid == 0) istore(&ready[b * 8 + p], READY_MAGIC);
  if (tid < 8) {
    while (iload(&ready[b * 8 + tid]) != READY_MAGIC)
      __builtin_amdgcn_s_sleep(1);
  }
  __syncthreads();

  auto dotIH = [&](const float* x) {
    float a = 0.0f;
    #pragma unroll
    for (int c = 0; c < 8; ++c) {
      int cc = (c + s) & 7;
      float4 xv = *(const float4*)(x + k0 + cc * 4);
      float4 w = wihr[c];
      a += w.x * xv.x + w.y * xv.y + w.z * xv.z + w.w * xv.w;
    }
    return a;
  };
  auto dotHH = [&]() {
    float a = 0.0f;
    #pragma unroll
    for (int c = 0; c < 8; ++c) {
      int cc = (c + s) & 7;
      float4 xv = *(const float4*)(hL + k0 + cc * 4);
      float4 w = whhr[c];
      a += w.x * xv.x + w.y * xv.y + w.z * xv.z + w.w * xv.w;
    }
    return a;
  };

  const float encih = dotIH(encL);
  float cv = 0.0f;
  U2 bk = tf2x32(0u, 42u, 0u, (uint32_t)b);
  int k = 1, step = 0;
  float lpAcc = 0.0f, entAcc = 0.0f;

  auto cell = [&](float gacc, int mode, int aid, int cid) {
    partL[tid] = gacc;
    __syncthreads();
    if (tid < 128) {
      float ssum = 0.0f;
      #pragma unroll
      for (int j = 0; j < 8; ++j) ssum += partL[tid * 8 + j];
      rowSumL[tid] = ssum + biasS[tid];
    }
    __syncthreads();
    if (tid < 32) {
      float gi = rowSumL[tid],       gf = rowSumL[32 + tid];
      float gg2 = rowSumL[64 + tid], go = rowSumL[96 + tid];
      float c2 = sigf(gf) * cv + sigf(gi) * tanhf(gg2);
      float h2 = sigf(go) * tanhf(c2);
      cv = c2;
      h2S[tid] = h2;
      if (mode == 2 && b == NBLK - 1) {
        out[62 + p * 32 + tid] = cv;
        out[318 + p * 32 + tid] = h2;
      }
    }
    __syncthreads();
    if (mode == 2) return;
    {
      const float* wc = (mode == 1) ? w1c : w2c;
      float yp = 0.0f;
      #pragma unroll
      for (int j = 0; j < 8; ++j) yp += wc[j] * h2S[ks * 8 + j];
      atomicAdd(&acc[(k % 3) * (NBLK * 256) + b * 256 + rr],
                __float2int_rn(yp * FXS));
      if (tid < 32)
        istore(&acc[((k + 1) % 3) * (NBLK * 256) + b * 256 + p * 32 + tid], 0);
    }
    __syncthreads();
    if (tid < 32) {
      u64 pk = ((u64)(uint32_t)k << 32) | (u64)__float_as_uint(h2S[tid]);
      hstore(&hp[(k & 1) * (NBLK * 256) + b * 256 + p * 32 + tid], pk);
    }
    if (tid < 256) {
      u64 v;
      const u64* src = &hp[(k & 1) * (NBLK * 256) + b * 256 + tid];
      while ((int)(hload(src) >> 32) != k) __builtin_amdgcn_s_sleep(1);
      v = hload(src);
      float hv = __uint_as_float((uint32_t)v);
      hL[tid] = hv;
      if (mode == 1 && cid >= 0) anchL[cid][tid] = hv;
    }
    __syncthreads();
    if (tid < 256) {
      int iv = iload(&acc[(k % 3) * (NBLK * 256) + b * 256 + tid]);
      float f = (float)((double)iv * (1.0 / 67108864.0));
      if (mode == 1) aw1S[aid][tid] = f; else w2hS[tid] = f;
    }
    __syncthreads();
    ++k;
  };

  auto sample = [&](int L) -> int {
    int wv = tid >> 6, lane = tid & 63;
    if (wv < L) {
      float a = 0.0f;
      #pragma unroll
      for (int j = 0; j < 4; ++j) {
        int kk = lane * 4 + j;
        a += tanhf(aw1S[wv][kk] + w2hS[kk]) * vL[kk];
      }
      a += __shfl_down(a, 32);
      a += __shfl_down(a, 16);
      a += __shfl_down(a, 8);
      a += __shfl_down(a, 4);
      a += __shfl_down(a, 2);
      a += __shfl_down(a, 1);
      if (lane == 0) logitL[wv] = a;
    }
    __syncthreads();
    if (tid < 64) {
      float lg = 0.0f, sgum = -1e30f;
      if (tid < L) {
        lg = 1.1f * tanhf(logitL[tid] * 0.2f);
        U2 sk = tf2x32(bk.x, bk.y, 0u, (uint32_t)step);
        U2 r2 = tf2x32(sk.x, sk.y, 0u, (uint32_t)tid);
        uint32_t bits = r2.x ^ r2.y;
        float u = __uint_as_float((bits >> 9) | 0x3f800000u) - 1.0f;
        u = fmaxf(TINYF, u + TINYF);
        sgum = lg - logf(-logf(u));
      }
      int bi = 0;
      float best = __shfl(sgum, 0, 64);
      for (int j = 1; j < L; ++j) {
        float sj = __shfl(sgum, j, 64);
        if (sj > best) { best = sj; bi = j; }
      }
      float mx = __shfl(lg, 0, 64);
      for (int j = 1; j < L; ++j) mx = fmaxf(mx, __shfl(lg, j, 64));
      float se = 0.0f;
      for (int j = 0; j < L; ++j) se += expf(__shfl(lg, j, 64) - mx);
      float lse = logf(se);
      float lgbi = __shfl(lg, bi, 64);
      float es = 0.0f;
      for (int j = 0; j < L; ++j) {
        float l = __shfl(lg, j, 64) - mx - lse;
        es += l * expf(l);
      }
      if (tid == 0) {
        lpAcc += -(lgbi - mx - lse);
        entAcc += -es;
        selL = bi;
        if (p == 0) out[b * 10 + step] = (float)bi;
      }
    }
    __syncthreads();
    step++;
    return selL;
  };

  cell(encih, 1, 0, -1);
  if (tid < 256) aw1S[1][tid] = aw1S[0][tid];
  __syncthreads();
  for (int L = 2; L <= 6; ++L) {
    cell(encih + dotHH(), 0, 0, -1);
    int s1v = sample(L);
    {
      float a = (s1v >= 2) ? dotIH(&anchL[s1v - 2][0]) : 0.0f;
      cell(a + dotHH(), 0, 0, -1);
    }
    int s2v = sample(L);
    {
      float a = (s2v >= 2) ? dotIH(&anchL[s2v - 2][0]) : 0.0f;
      if (L < 6) cell(a + dotHH(), 1, L, L - 2);
      else       cell(a + dotHH(), 2, 0, -1);
    }
  }
  if (p == 0 && tid == 0) {
    fstore(&part[2 * b], lpAcc);
    fstore(&part[2 * b + 1], entAcc);
    __builtin_amdgcn_s_waitcnt(0);
    istore(&done[b], DONE_MAGIC);
    if (b == NBLK - 1) {
      float lp = 0.0f, en = 0.0f;
      for (int j = 0; j < NBLK; ++j) {
        while (iload(&done[j]) != DONE_MAGIC) __builtin_amdgcn_s_sleep(1);
        lp += fload(&part[2 * j]);
        en += fload(&part[2 * j + 1]);
      }
      out[60] = lp;
      out[61] = en;
    }
  }
}

extern "C" void kernel_launch(void* const* d_in, const int* in_sizes, int n_in,
                              void* d_out, int out_size, void* d_ws, size_t ws_size,
                              hipStream_t stream) {
  const float* enc = (const float*)d_in[0];
  const float* wih = (const float*)d_in[1];
  const float* whh = (const float*)d_in[2];
  const float* bih = (const float*)d_in[3];
  const float* bhh = (const float*)d_in[4];
  const float* w1  = (const float*)d_in[5];
  const float* w2  = (const float*)d_in[6];
  const float* v   = (const float*)d_in[7];
  unsigned char* ws = (unsigned char*)d_ws;
  float* out = (float*)d_out;

  if (ws_size >= W_NEED) {
    ctrl_v20<<<dim3(64), dim3(THR), 0, stream>>>(
        enc, wih, whh, bih, bhh, w1, w2, v, ws, out);
  } else {
    ctrl_small<<<dim3(64), dim3(1024), 0, stream>>>(
        enc, wih, whh, bih, bhh, w1, w2, v, ws, out);
  }
}

// Round 10
// 145.474 us; speedup vs baseline: 1.0817x; 1.0817x over previous
//
#include <hip/hip_runtime.h>
#include <stdint.h>

// ENAS LSTM controller. R21: champion restore (== R19 verbatim, bench 146.8).
//  - R20 post-mortem: in-exchange sampling REGRESSED (92-93us warm vs 84-86;
//    bench 157.4). The sampling work stayed on the barrier path (before vs
//    after the closing barrier is equivalent), plus two busy-spin LDS-atomic
//    syncs contended with the polling waves. Reverted.
//  - Final structure (R16 skeleton + R18's fused nonlin):
//    * 8 wgs/chain, register-resident weights (128 VGPR-floats/thread).
//    * Per cell: fused gate reduce+nonlin (tid<32) -> h publish (tagged
//      u64 words) -> y partials publish -> h poll (tid<256) || wg0 y-gather
//      (batched 8-load, tid>=256) -> closing barrier. ONE LLC RT/cell.
//    * Sampled cells: wg0 resolves (logits+threefry+selection) and
//      publishes a self-validating idx word; peers overlap the poll with
//      dotHH. (Decentralized sampling lost 3x: R12/R13/R17.)
//  - Structural floor: 15 sequential agent-scope LLC RTs x ~4.5us
//    (word-count-independent; R7: 40w/4.1us) + idx waits ~= 84us warm.
//    HBM 1.7%, VALU 2% -> latency-chain regime, no BW/compute roofline.
//    Falsified: XCD-L2 transport (R14), decentralized sampling (x3),
//    compute compression (R18), in-exchange sampling (R20).
//  - ws layout: 221,504 <= proven 221,696; R8 fallback kept.

#define NBLK  6
#define PWG   8
#define THR   512
#define TINYF 1.17549435e-38f
#define HTAGB 0xC3B00000u
#define YTAGB 0xE1700000u
#define ITAGB 0xA5D00000u
#define DONE_MAGIC 0x444f4e45

typedef unsigned long long u64;
struct U2 { uint32_t x, y; };

// ---- ws layout (bytes) ----
#define W_DONE 0u        // int[8]                (32)
#define W_PART 32u       // float[12]             (48)
#define W_IDX  80u       // u32[6][10] = 240
#define W_HX   320u      // u64[2][6][256] = 24576
#define W_YMB  24896u    // u64[2][6][8][256] = 196608 (64B-aligned)
#define W_NEED 221504u

// ---- fallback (R8/R10 small) ws layout ----
#define S_READY 0u
#define S_DONE  192u
#define S_PART  224u
#define S_HP    320u
#define S_ACC   24896u
#define FXS     67108864.0f
#define READY_MAGIC 0x52454459

// Threefry-2x32, 20 rounds (Random123 / JAX). Key (k0,k1), counter (c0,c1).
__device__ __forceinline__ U2 tf2x32(uint32_t k0, uint32_t k1,
                                     uint32_t c0, uint32_t c1) {
  uint32_t ks2 = k0 ^ k1 ^ 0x1BD11BDAu;
  uint32_t x0 = c0 + k0, x1 = c1 + k1;
#define TFR(r) { x0 += x1; x1 = (x1 << (r)) | (x1 >> (32 - (r))); x1 ^= x0; }
  TFR(13) TFR(15) TFR(26) TFR(6)   x0 += k1;  x1 += ks2 + 1u;
  TFR(17) TFR(29) TFR(16) TFR(24)  x0 += ks2; x1 += k0 + 2u;
  TFR(13) TFR(15) TFR(26) TFR(6)   x0 += k0;  x1 += k1 + 3u;
  TFR(17) TFR(29) TFR(16) TFR(24)  x0 += k1;  x1 += ks2 + 4u;
  TFR(13) TFR(15) TFR(26) TFR(6)   x0 += ks2; x1 += k0 + 5u;
#undef TFR
  U2 r; r.x = x0; r.y = x1; return r;
}

__device__ __forceinline__ float sigf(float x) {
  return 1.0f / (1.0f + expf(-x));
}
// relaxed agent-scope (LLC-resolved) accessors -- the only sync primitives.
__device__ __forceinline__ void istore(int* p, int v) {
  __hip_atomic_store(p, v, __ATOMIC_RELAXED, __HIP_MEMORY_SCOPE_AGENT);
}
__device__ __forceinline__ int iload(const int* p) {
  return __hip_atomic_load(p, __ATOMIC_RELAXED, __HIP_MEMORY_SCOPE_AGENT);
}
__device__ __forceinline__ void hstore(u64* p, u64 v) {
  __hip_atomic_store(p, v, __ATOMIC_RELAXED, __HIP_MEMORY_SCOPE_AGENT);
}
__device__ __forceinline__ u64 hload(const u64* p) {
  return __hip_atomic_load(p, __ATOMIC_RELAXED, __HIP_MEMORY_SCOPE_AGENT);
}
__device__ __forceinline__ void fstore(float* p, float v) {
  __hip_atomic_store(p, v, __ATOMIC_RELAXED, __HIP_MEMORY_SCOPE_AGENT);
}
__device__ __forceinline__ float fload(const float* p) {
  return __hip_atomic_load(p, __ATOMIC_RELAXED, __HIP_MEMORY_SCOPE_AGENT);
}
__device__ __forceinline__ u64 pollw(const u64* p, uint32_t want) {
  u64 v;
  for (;;) {
    v = hload(p);
    if ((uint32_t)(v >> 32) == want) return v;
    __builtin_amdgcn_s_sleep(1);
  }
}

// =================== R21 kernel ============================================
__global__ __launch_bounds__(THR, 2) void ctrl_v21(
    const float* __restrict__ enc_w,
    const float* __restrict__ wih,
    const float* __restrict__ whh,
    const float* __restrict__ b_ih,
    const float* __restrict__ b_hh,
    const float* __restrict__ w1,
    const float* __restrict__ w2,
    const float* __restrict__ vvec,
    unsigned char* __restrict__ ws,
    float* __restrict__ out) {

  const int b = blockIdx.x & 7;      // XCD swizzle: chain b -> XCD b (if RR)
  const int p = blockIdx.x >> 3;
  if (b >= NBLK) return;
  const int tid = threadIdx.x;

  int*   done = (int*)(ws + W_DONE);
  float* part = (float*)(ws + W_PART);
  int*   idxw = (int*)(ws + W_IDX);   // u32 self-validating idx words
  u64*   hx   = (u64*)(ws + W_HX);    // [2][6][256] tagged h words
  u64*   ymb  = (u64*)(ws + W_YMB);   // [2][6][8][256] tagged y words

  // gate GEMV: 128 local rows x 4 k-slices of 64; s wave-uniform -> all LDS
  // x-vector reads are broadcasts (0 bank conflicts, proven R11/R16).
  const int rl = tid & 127, s = tid >> 7;
  const int grow = (rl >> 5) * 256 + p * 32 + (rl & 31);
  const int k0 = s * 64;
  // y-partial: element rr, col half ks (cols p*32 + ks*16 + j)
  const int rr = tid & 255, ks = tid >> 8;
  const int cb = p * 32 + ks * 16;

  __shared__ __align__(16) float gateL[THR];
  __shared__ __align__(16) float hL[256], encL[256], vL[256];
  __shared__ __align__(16) float anchL[4][256];
  __shared__ __align__(16) float w2hS[256], aw1S[6][256];
  __shared__ float biasS[128], h2S[32];
  __shared__ float logitL[8];
  __shared__ int   selL;

  if (tid < 256) { encL[tid] = enc_w[tid]; vL[tid] = vvec[tid]; }
  if (tid < 128) {
    int r = (tid >> 5) * 256 + p * 32 + (tid & 31);
    biasS[tid] = b_ih[r] + b_hh[r];
  }

  // weights: unified VGPR/AGPR file keeps these resident (R11-proven)
  float4 wihr[16], whhr[16];
  #pragma unroll
  for (int c = 0; c < 16; ++c) {
    wihr[c] = *(const float4*)(wih + grow * 256 + k0 + c * 4);
    whhr[c] = *(const float4*)(whh + grow * 256 + k0 + c * 4);
  }
  float w1c[16], w2c[16];
  #pragma unroll
  for (int j = 0; j < 16; ++j) {
    w1c[j] = w1[rr * 256 + cb + j];
    w2c[j] = w2[rr * 256 + cb + j];
  }
  __syncthreads();

  auto dotIH = [&](const float* x) {
    float a = 0.0f;
    #pragma unroll
    for (int c = 0; c < 16; ++c) {
      float4 xv = *(const float4*)(x + k0 + c * 4);
      float4 w = wihr[c];
      a += w.x * xv.x + w.y * xv.y + w.z * xv.z + w.w * xv.w;
    }
    return a;
  };
  auto dotHH = [&]() {
    float a = 0.0f;
    #pragma unroll
    for (int c = 0; c < 16; ++c) {
      float4 xv = *(const float4*)(hL + k0 + c * 4);
      float4 w = whhr[c];
      a += w.x * xv.x + w.y * xv.y + w.z * xv.z + w.w * xv.w;
    }
    return a;
  };

  const float encih = dotIH(encL);   // wih @ enc, reused by all enc cells

  float cv = 0.0f;                            // c for element p*32+tid (tid<32)
  U2 bk = tf2x32(0u, 42u, 0u, (uint32_t)b);   // fold_in(key(42), b)
  int k = 1, step = 0;
  float lpAcc = 0.0f, entAcc = 0.0f;

  // One cell + exchange. mode 0: y = w2@h -> w2hS (wg0 only);
  // mode 1: y = w1@h -> aw1S[aid] (wg0) + anchor h -> anchL[cid] (all wgs);
  // mode 2: last cell (no exchange).
  // Fused reduce+nonlin (R18-verified): tid<32 reads 16 slices directly,
  // ascending-j sum + bias == R16 bits; deletes rowSumL stage + 1 barrier.
  auto cell = [&](float gacc, int mode, int aid, int cid) {
    gateL[tid] = gacc;                       // tid = s*128 + rl
    __syncthreads();
    if (tid < 32) {
      float rs[4];
      #pragma unroll
      for (int g = 0; g < 4; ++g) {
        float ssum = 0.0f;
        #pragma unroll
        for (int j = 0; j < 4; ++j) ssum += gateL[j * 128 + g * 32 + tid];
        rs[g] = ssum + biasS[g * 32 + tid];
      }
      float gi = rs[0], gf = rs[1], gg2 = rs[2], go = rs[3];
      float c2 = sigf(gf) * cv + sigf(gi) * tanhf(gg2);
      float h2 = sigf(go) * tanhf(c2);
      cv = c2;
      h2S[tid] = h2;
      if (mode == 2) {
        if (b == NBLK - 1) { out[62 + p * 32 + tid] = cv; out[318 + p * 32 + tid] = h2; }
      } else {                               // publish own h ASAP (tagged)
        hstore(&hx[(k & 1) * 1536 + b * 256 + p * 32 + tid],
               ((u64)(HTAGB | (uint32_t)k) << 32) | (u64)__float_as_uint(h2));
      }
    }
    __syncthreads();                         // h2S visible; gateL reusable
    if (mode == 2) return;

    {                                        // own y partial (16 cols each)
      const float* wc = (mode == 1) ? w1c : w2c;
      float yp = 0.0f;
      #pragma unroll
      for (int j = 0; j < 16; ++j) yp += wc[j] * h2S[ks * 16 + j];
      gateL[tid] = yp;                       // layout ks*256 + rr
    }
    __syncthreads();

    const uint32_t wantY = YTAGB | (uint32_t)k;
    const uint32_t wantH = HTAGB | (uint32_t)k;
    u64* ybase = ymb + (size_t)(k & 1) * 12288 + (size_t)b * 2048; // [8][256]
    if (tid < 256) {
      // publish self-validating y word: (tag|f32), value = A+B bits == R16.
      float yp2 = gateL[tid] + gateL[256 + tid];
      hstore(ybase + (size_t)p * 256 + tid,
             ((u64)wantY << 32) | (u64)__float_as_uint(yp2));
      // then poll full h (each lane stops once its word is valid)
      u64 v = pollw(&hx[(k & 1) * 1536 + b * 256 + tid], wantH);
      float hv = __uint_as_float((uint32_t)v);
      hL[tid] = hv;
      if (mode == 1 && cid >= 0) anchL[cid][tid] = hv;
    } else if (p == 0) {
      // wg0 waves 4-7: gather the 8 y partials for element e CONCURRENTLY
      // with the h-poll. 8 independent hloads (compiler-batched, one RT),
      // all tags checked together, retry. Sum ascending p == R16 order.
      const int e = tid - 256;
      const u64* bp = ybase + e;
      u64 w[8];
      for (;;) {
        #pragma unroll
        for (int q = 0; q < 8; ++q) w[q] = hload(bp + q * 256);
        uint32_t bad = 0u;
        #pragma unroll
        for (int q = 0; q < 8; ++q) bad |= ((uint32_t)(w[q] >> 32) ^ wantY);
        if (bad == 0u) break;
        __builtin_amdgcn_s_sleep(1);
      }
      float y = 0.0f;
      #pragma unroll
      for (int q = 0; q < 8; ++q) y += __uint_as_float((uint32_t)w[q]);
      if (mode == 1) aw1S[aid][e] = y; else w2hS[e] = y;
    }
    __syncthreads();
    ++k;
  };

  // Centralized sampling (R16): wg0 samples + broadcasts a self-validating
  // u32 idx word; peers poll it (overlapped with dotHH at the call site).
  auto resolve = [&](int L) -> int {
    if (p == 0) {
      int wv = tid >> 6, lane = tid & 63;
      if (wv < L) {
        float a = 0.0f;
        #pragma unroll
        for (int j = 0; j < 4; ++j) {        // stride-64: conflict-free
          int kk = j * 64 + lane;
          a += tanhf(aw1S[wv][kk] + w2hS[kk]) * vL[kk];
        }
        a += __shfl_down(a, 32);
        a += __shfl_down(a, 16);
        a += __shfl_down(a, 8);
        a += __shfl_down(a, 4);
        a += __shfl_down(a, 2);
        a += __shfl_down(a, 1);
        if (lane == 0) logitL[wv] = a;
      }
      __syncthreads();
      if (tid < 64) {                        // wave 0: selection (R10 math)
        float lg = 0.0f, sgum = -1e30f;
        if (tid < L) {
          lg = 1.1f * tanhf(logitL[tid] * 0.2f);
          U2 sk = tf2x32(bk.x, bk.y, 0u, (uint32_t)step);
          U2 r2 = tf2x32(sk.x, sk.y, 0u, (uint32_t)tid);
          uint32_t bits = r2.x ^ r2.y;
          float u = __uint_as_float((bits >> 9) | 0x3f800000u) - 1.0f;
          u = fmaxf(TINYF, u + TINYF);       // jax uniform(tiny, 1)
          sgum = lg - logf(-logf(u));
        }
        int bi = 0;
        float best = __shfl(sgum, 0, 64);
        for (int j = 1; j < L; ++j) {
          float sj = __shfl(sgum, j, 64);
          if (sj > best) { best = sj; bi = j; }   // first-max = jnp.argmax
        }
        float mx = __shfl(lg, 0, 64);
        for (int j = 1; j < L; ++j) mx = fmaxf(mx, __shfl(lg, j, 64));
        float se = 0.0f;
        for (int j = 0; j < L; ++j) se += expf(__shfl(lg, j, 64) - mx);
        float lse = logf(se);
        float lgbi = __shfl(lg, bi, 64);
        float es = 0.0f;
        for (int j = 0; j < L; ++j) {
          float l = __shfl(lg, j, 64) - mx - lse;
          es += l * expf(l);
        }
        if (tid == 0) {
          lpAcc += -(lgbi - mx - lse);
          entAcc += -es;
          selL = bi;
          out[b * 10 + step] = (float)bi;
          istore(&idxw[b * 10 + step],
                 (int)(ITAGB | ((uint32_t)step << 4) | (uint32_t)bi));
        }
      }
      __syncthreads();
    } else {
      if (tid == 0) {
        const uint32_t want = ITAGB | ((uint32_t)step << 4);
        for (;;) {
          uint32_t v = (uint32_t)iload(&idxw[b * 10 + step]);
          if ((v & 0xFFFFFFF0u) == want) { selL = (int)(v & 15u); break; }
          __builtin_amdgcn_s_sleep(1);
        }
      }
      __syncthreads();
    }
    step++;
    return selL;
  };

  // ---- chain ----
  cell(encih, 1, 0, -1);             // zero-state cell; wg0 gets aw1[0]
  if (p == 0) {
    if (tid < 256) aw1S[1][tid] = aw1S[0][tid];
    __syncthreads();
  }

  for (int L = 2; L <= 6; ++L) {
    { float hh = dotHH(); cell(encih + hh, 0, 0, -1); }          // cellA
    {
      int s1; float hh;
      if (p == 0) { s1 = resolve(L); hh = dotHH(); }             // idx ASAP
      else        { hh = dotHH(); s1 = resolve(L); }             // overlap wait
      float a = (s1 >= 2) ? dotIH(&anchL[s1 - 2][0]) : 0.0f;
      cell(a + hh, 0, 0, -1);                                    // cellB
    }
    {
      int s2; float hh;
      if (p == 0) { s2 = resolve(L); hh = dotHH(); }
      else        { hh = dotHH(); s2 = resolve(L); }
      float a = (s2 >= 2) ? dotIH(&anchL[s2 - 2][0]) : 0.0f;
      if (L < 6) cell(a + hh, 1, L, L - 2);                      // cellC anchor
      else       cell(a + hh, 2, 0, -1);                         // last cell
    }
  }

  if (p == 0 && tid == 0) {
    fstore(&part[2 * b], lpAcc);
    fstore(&part[2 * b + 1], entAcc);
    __builtin_amdgcn_s_waitcnt(0);
    istore(&done[b], DONE_MAGIC);
    if (b == NBLK - 1) {
      float lp = 0.0f, en = 0.0f;
      for (int j = 0; j < NBLK; ++j) {
        while (iload(&done[j]) != DONE_MAGIC) __builtin_amdgcn_s_sleep(1);
        lp += fload(&part[2 * j]);
        en += fload(&part[2 * j + 1]);
      }
      out[60] = lp;
      out[61] = en;
    }
  }
}

// =================== fallback (proven R8-style; small ws) ==================
__global__ __launch_bounds__(1024) void ctrl_small(
    const float* __restrict__ enc_w,
    const float* __restrict__ wih,
    const float* __restrict__ whh,
    const float* __restrict__ b_ih,
    const float* __restrict__ b_hh,
    const float* __restrict__ w1,
    const float* __restrict__ w2,
    const float* __restrict__ vvec,
    unsigned char* __restrict__ ws,
    float* __restrict__ out) {

  const int b = blockIdx.x & 7;
  const int p = blockIdx.x >> 3;
  if (b >= NBLK) return;
  const int tid = threadIdx.x;

  int*   ready = (int*)(ws + S_READY);
  int*   done  = (int*)(ws + S_DONE);
  float* part  = (float*)(ws + S_PART);
  u64*   hp    = (u64*)(ws + S_HP);
  int*   acc   = (int*)(ws + S_ACC);

  const int rl = tid >> 3, s = tid & 7;
  const int g = rl >> 5, el = rl & 31;
  const int row = g * 256 + p * 32 + el;
  const int k0 = s * 32;
  const int rr = tid & 255, ks = tid >> 8;

  __shared__ __align__(16) float hL[256], encL[256], vL[256];
  __shared__ __align__(16) float anchL[4][256];
  __shared__ __align__(16) float partL[1024];
  __shared__ __align__(16) float w2hS[256], aw1S[6][256];
  __shared__ float rowSumL[128], biasS[128], h2S[32];
  __shared__ float logitL[8];
  __shared__ int   selL;

  if (tid < 256) { encL[tid] = enc_w[tid]; vL[tid] = vvec[tid]; }
  if (tid < 128) {
    int gg = tid >> 5, ee = tid & 31, r = gg * 256 + p * 32 + ee;
    biasS[tid] = b_ih[r] + b_hh[r];
  }

  float4 wihr[8], whhr[8];
  #pragma unroll
  for (int c = 0; c < 8; ++c) {
    int cc = (c + s) & 7;
    wihr[c] = *(const float4*)(wih + row * 256 + k0 + cc * 4);
    whhr[c] = *(const float4*)(whh + row * 256 + k0 + cc * 4);
  }
  float w1c[8], w2c[8];
  #pragma unroll
  for (int j = 0; j < 8; ++j) {
    w1c[j] = w1[rr * 256 + p * 32 + ks * 8 + j];
    w2c[j] = w2[rr * 256 + p * 32 + ks * 8 + j];
  }

  if (tid < 32) istore(&acc[1 * (NBLK * 256) + b * 256 + p * 32 + tid], 0);
  __syncthreads();
  if (tid == 0) istore(&ready[b * 8 + p], READY_MAGIC);
  if (tid < 8) {
    while (iload(&ready[b * 8 + tid]) != READY_MAGIC)
      __builtin_amdgcn_s_sleep(1);
  }
  __syncthreads();

  auto dotIH = [&](const float* x) {
    float a = 0.0f;
    #pragma unroll
    for (int c = 0; c < 8; ++c) {
      int cc = (c + s) & 7;
      float4 xv = *(const float4*)(x + k0 + cc * 4);
      float4 w = wihr[c];
      a += w.x * xv.x + w.y * xv.y + w.z * xv.z + w.w * xv.w;
    }
    return a;
  };
  auto dotHH = [&]() {
    float a = 0.0f;
    #pragma unroll
    for (int c = 0; c < 8; ++c) {
      int cc = (c + s) & 7;
      float4 xv = *(const float4*)(hL + k0 + cc * 4);
      float4 w = whhr[c];
      a += w.x * xv.x + w.y * xv.y + w.z * xv.z + w.w * xv.w;
    }
    return a;
  };

  const float encih = dotIH(encL);
  float cv = 0.0f;
  U2 bk = tf2x32(0u, 42u, 0u, (uint32_t)b);
  int k = 1, step = 0;
  float lpAcc = 0.0f, entAcc = 0.0f;

  auto cell = [&](float gacc, int mode, int aid, int cid) {
    partL[tid] = gacc;
    __syncthreads();
    if (tid < 128) {
      float ssum = 0.0f;
      #pragma unroll
      for (int j = 0; j < 8; ++j) ssum += partL[tid * 8 + j];
      rowSumL[tid] = ssum + biasS[tid];
    }
    __syncthreads();
    if (tid < 32) {
      float gi = rowSumL[tid],       gf = rowSumL[32 + tid];
      float gg2 = rowSumL[64 + tid], go = rowSumL[96 + tid];
      float c2 = sigf(gf) * cv + sigf(gi) * tanhf(gg2);
      float h2 = sigf(go) * tanhf(c2);
      cv = c2;
      h2S[tid] = h2;
      if (mode == 2 && b == NBLK - 1) {
        out[62 + p * 32 + tid] = cv;
        out[318 + p * 32 + tid] = h2;
      }
    }
    __syncthreads();
    if (mode == 2) return;
    {
      const float* wc = (mode == 1) ? w1c : w2c;
      float yp = 0.0f;
      #pragma unroll
      for (int j = 0; j < 8; ++j) yp += wc[j] * h2S[ks * 8 + j];
      atomicAdd(&acc[(k % 3) * (NBLK * 256) + b * 256 + rr],
                __float2int_rn(yp * FXS));
      if (tid < 32)
        istore(&acc[((k + 1) % 3) * (NBLK * 256) + b * 256 + p * 32 + tid], 0);
    }
    __syncthreads();
    if (tid < 32) {
      u64 pk = ((u64)(uint32_t)k << 32) | (u64)__float_as_uint(h2S[tid]);
      hstore(&hp[(k & 1) * (NBLK * 256) + b * 256 + p * 32 + tid], pk);
    }
    if (tid < 256) {
      u64 v;
      const u64* src = &hp[(k & 1) * (NBLK * 256) + b * 256 + tid];
      while ((int)(hload(src) >> 32) != k) __builtin_amdgcn_s_sleep(1);
      v = hload(src);
      float hv = __uint_as_float((uint32_t)v);
      hL[tid] = hv;
      if (mode == 1 && cid >= 0) anchL[cid][tid] = hv;
    }
    __syncthreads();
    if (tid < 256) {
      int iv = iload(&acc[(k % 3) * (NBLK * 256) + b * 256 + tid]);
      float f = (float)((double)iv * (1.0 / 67108864.0));
      if (mode == 1) aw1S[aid][tid] = f; else w2hS[tid] = f;
    }
    __syncthreads();
    ++k;
  };

  auto sample = [&](int L) -> int {
    int wv = tid >> 6, lane = tid & 63;
    if (wv < L) {
      float a = 0.0f;
      #pragma unroll
      for (int j = 0; j < 4; ++j) {
        int kk = lane * 4 + j;
        a += tanhf(aw1S[wv][kk] + w2hS[kk]) * vL[kk];
      }
      a += __shfl_down(a, 32);
      a += __shfl_down(a, 16);
      a += __shfl_down(a, 8);
      a += __shfl_down(a, 4);
      a += __shfl_down(a, 2);
      a += __shfl_down(a, 1);
      if (lane == 0) logitL[wv] = a;
    }
    __syncthreads();
    if (tid < 64) {
      float lg = 0.0f, sgum = -1e30f;
      if (tid < L) {
        lg = 1.1f * tanhf(logitL[tid] * 0.2f);
        U2 sk = tf2x32(bk.x, bk.y, 0u, (uint32_t)step);
        U2 r2 = tf2x32(sk.x, sk.y, 0u, (uint32_t)tid);
        uint32_t bits = r2.x ^ r2.y;
        float u = __uint_as_float((bits >> 9) | 0x3f800000u) - 1.0f;
        u = fmaxf(TINYF, u + TINYF);
        sgum = lg - logf(-logf(u));
      }
      int bi = 0;
      float best = __shfl(sgum, 0, 64);
      for (int j = 1; j < L; ++j) {
        float sj = __shfl(sgum, j, 64);
        if (sj > best) { best = sj; bi = j; }
      }
      float mx = __shfl(lg, 0, 64);
      for (int j = 1; j < L; ++j) mx = fmaxf(mx, __shfl(lg, j, 64));
      float se = 0.0f;
      for (int j = 0; j < L; ++j) se += expf(__shfl(lg, j, 64) - mx);
      float lse = logf(se);
      float lgbi = __shfl(lg, bi, 64);
      float es = 0.0f;
      for (int j = 0; j < L; ++j) {
        float l = __shfl(lg, j, 64) - mx - lse;
        es += l * expf(l);
      }
      if (tid == 0) {
        lpAcc += -(lgbi - mx - lse);
        entAcc += -es;
        selL = bi;
        if (p == 0) out[b * 10 + step] = (float)bi;
      }
    }
    __syncthreads();
    step++;
    return selL;
  };

  cell(encih, 1, 0, -1);
  if (tid < 256) aw1S[1][tid] = aw1S[0][tid];
  __syncthreads();
  for (int L = 2; L <= 6; ++L) {
    cell(encih + dotHH(), 0, 0, -1);
    int s1v = sample(L);
    {
      float a = (s1v >= 2) ? dotIH(&anchL[s1v - 2][0]) : 0.0f;
      cell(a + dotHH(), 0, 0, -1);
    }
    int s2v = sample(L);
    {
      float a = (s2v >= 2) ? dotIH(&anchL[s2v - 2][0]) : 0.0f;
      if (L < 6) cell(a + dotHH(), 1, L, L - 2);
      else       cell(a + dotHH(), 2, 0, -1);
    }
  }
  if (p == 0 && tid == 0) {
    fstore(&part[2 * b], lpAcc);
    fstore(&part[2 * b + 1], entAcc);
    __builtin_amdgcn_s_waitcnt(0);
    istore(&done[b], DONE_MAGIC);
    if (b == NBLK - 1) {
      float lp = 0.0f, en = 0.0f;
      for (int j = 0; j < NBLK; ++j) {
        while (iload(&done[j]) != DONE_MAGIC) __builtin_amdgcn_s_sleep(1);
        lp += fload(&part[2 * j]);
        en += fload(&part[2 * j + 1]);
      }
      out[60] = lp;
      out[61] = en;
    }
  }
}

extern "C" void kernel_launch(void* const* d_in, const int* in_sizes, int n_in,
                              void* d_out, int out_size, void* d_ws, size_t ws_size,
                              hipStream_t stream) {
  const float* enc = (const float*)d_in[0];
  const float* wih = (const float*)d_in[1];
  const float* whh = (const float*)d_in[2];
  const float* bih = (const float*)d_in[3];
  const float* bhh = (const float*)d_in[4];
  const float* w1  = (const float*)d_in[5];
  const float* w2  = (const float*)d_in[6];
  const float* v   = (const float*)d_in[7];
  unsigned char* ws = (unsigned char*)d_ws;
  float* out = (float*)d_out;

  if (ws_size >= W_NEED) {
    ctrl_v21<<<dim3(64), dim3(THR), 0, stream>>>(
        enc, wih, whh, bih, bhh, w1, w2, v, ws, out);
  } else {
    ctrl_small<<<dim3(64), dim3(1024), 0, stream>>>(
        enc, wih, whh, bih, bhh, w1, w2, v, ws, out);
  }
}